// Round 1
// baseline (5183.407 us; speedup 1.0000x reference)
//
#include <hip/hip_runtime.h>

#define Bc 2
#define Tt 2048
#define Dd 1024
#define Hh 16
#define KVHh 4
#define HDd 64
#define NGROUPS 4

// ---------------------------------------------------------------------------
// Generic fp32 GEMM: C[M][N] = A[M][K] @ W[K][N].  64x64 tile, 4x4/thread.
// ---------------------------------------------------------------------------
__global__ __launch_bounds__(256) void gemm_f32(const float* __restrict__ A,
                                                const float* __restrict__ W,
                                                float* __restrict__ C,
                                                int M, int N, int K) {
    __shared__ float As[64][17];   // +1 pad breaks bank conflicts
    __shared__ float Bs[16][65];
    const int tid = threadIdx.x;
    const int tx = tid & 15, ty = tid >> 4;
    const int bx = blockIdx.x, by = blockIdx.y;
    float acc[4][4] = {};
    for (int k0 = 0; k0 < K; k0 += 16) {
        #pragma unroll
        for (int s = 0; s < 4; ++s) {            // A tile 64x16
            int idx = tid + s * 256;
            int r = idx >> 4, kk = idx & 15;
            As[r][kk] = A[(size_t)(by * 64 + r) * K + k0 + kk];
        }
        #pragma unroll
        for (int s = 0; s < 4; ++s) {            // W tile 16x64
            int idx = tid + s * 256;
            int kk = idx >> 6, c = idx & 63;
            Bs[kk][c] = W[(size_t)(k0 + kk) * N + bx * 64 + c];
        }
        __syncthreads();
        #pragma unroll
        for (int kk = 0; kk < 16; ++kk) {
            float a[4], b[4];
            #pragma unroll
            for (int i = 0; i < 4; ++i) a[i] = As[ty * 4 + i][kk];
            #pragma unroll
            for (int j = 0; j < 4; ++j) b[j] = Bs[kk][tx * 4 + j];
            #pragma unroll
            for (int i = 0; i < 4; ++i)
                #pragma unroll
                for (int j = 0; j < 4; ++j)
                    acc[i][j] += a[i] * b[j];
        }
        __syncthreads();
    }
    #pragma unroll
    for (int i = 0; i < 4; ++i) {
        size_t r = (size_t)(by * 64 + ty * 4 + i) * N + bx * 64 + tx * 4;
        #pragma unroll
        for (int j = 0; j < 4; ++j) C[r + j] = acc[i][j];
    }
}

// ---------------------------------------------------------------------------
// RoPE in-place on [B*T][nh][64] buffer.  One thread per (bt, h, d<32) pair.
// ---------------------------------------------------------------------------
__global__ void rope_kernel(float* __restrict__ qk,
                            const float* __restrict__ cosb,
                            const float* __restrict__ sinb,
                            int nh, int total) {
    int i = blockIdx.x * blockDim.x + threadIdx.x;
    if (i >= total) return;
    int d = i & 31;
    int rem = i >> 5;
    int h = rem % nh;
    int bt = rem / nh;
    int t = bt % Tt;
    float c = cosb[t * 32 + d];
    float s = sinb[t * 32 + d];
    float* p = qk + ((size_t)bt * nh + h) * 64;
    float x1 = p[d], x2 = p[d + 32];
    p[d]      = x1 * c - x2 * s;
    p[d + 32] = x2 * c + x1 * s;
}

// ---------------------------------------------------------------------------
// Causal GQA flash attention: one wave per (b, h, q-row).  Lane = head dim.
// Online softmax; rescale only when the running max changes (wave-uniform).
// ---------------------------------------------------------------------------
__global__ __launch_bounds__(256) void attn_kernel(const float* __restrict__ Q,
                                                   const float* __restrict__ K,
                                                   const float* __restrict__ V,
                                                   float* __restrict__ O) {
    const int wave = threadIdx.x >> 6;
    const int lane = threadIdx.x & 63;
    const int gw = blockIdx.x * 4 + wave;        // global row id
    const int qi = gw % Tt;
    const int bh = gw / Tt;
    const int h = bh % Hh;
    const int b = bh / Hh;
    const int kvh = h / NGROUPS;
    const float scale = 0.125f;                  // 1/sqrt(64)

    float q = Q[(((size_t)b * Tt + qi) * Hh + h) * 64 + lane] * scale;
    float m = -1e30f, l = 0.f, acc = 0.f;
    const float* Kb = K + ((size_t)b * Tt * KVHh + kvh) * 64 + lane;
    const float* Vb = V + ((size_t)b * Tt * KVHh + kvh) * 64 + lane;

    for (int j = 0; j <= qi; ++j) {
        float kj = Kb[(size_t)j * KVHh * 64];
        float s = q * kj;
        #pragma unroll
        for (int off = 32; off > 0; off >>= 1) s += __shfl_xor(s, off, 64);
        float vj = Vb[(size_t)j * KVHh * 64];
        if (s <= m) {                            // wave-uniform branch
            float p = __expf(s - m);
            l += p;
            acc += p * vj;
        } else {
            float corr = __expf(m - s);          // exp(-inf)=0 on first iter
            l = l * corr + 1.f;
            acc = acc * corr + vj;
            m = s;
        }
    }
    O[(((size_t)b * Tt + qi) * Hh + h) * 64 + lane] = acc / l;
}

// ---------------------------------------------------------------------------
extern "C" void kernel_launch(void* const* d_in, const int* in_sizes, int n_in,
                              void* d_out, int out_size, void* d_ws, size_t ws_size,
                              hipStream_t stream) {
    const float* x  = (const float*)d_in[0];
    const float* rc = (const float*)d_in[1];
    const float* rs = (const float*)d_in[2];
    // d_in[3] attention_mask: exactly causal -1e9 -> handled structurally
    const float* Wq = (const float*)d_in[4];
    const float* Wk = (const float*)d_in[5];
    const float* Wv = (const float*)d_in[6];
    const float* Wo = (const float*)d_in[7];
    float* out = (float*)d_out;

    float* qbuf = (float*)d_ws;                     // 4096 x 1024
    float* kbuf = qbuf + (size_t)4096 * 1024;       // 4096 x 256
    float* vbuf = kbuf + (size_t)4096 * 256;        // 4096 x 256
    float* obuf = vbuf + (size_t)4096 * 256;        // 4096 x 1024

    dim3 blk(256);
    gemm_f32<<<dim3(16, 64), blk, 0, stream>>>(x, Wq, qbuf, 4096, 1024, 1024);
    gemm_f32<<<dim3(4, 64),  blk, 0, stream>>>(x, Wk, kbuf, 4096, 256, 1024);
    gemm_f32<<<dim3(4, 64),  blk, 0, stream>>>(x, Wv, vbuf, 4096, 256, 1024);

    rope_kernel<<<(2 * Tt * Hh * 32) / 256, 256, 0, stream>>>(qbuf, rc, rs, Hh, 2 * Tt * Hh * 32);
    rope_kernel<<<(2 * Tt * KVHh * 32) / 256, 256, 0, stream>>>(kbuf, rc, rs, KVHh, 2 * Tt * KVHh * 32);

    attn_kernel<<<(2 * Hh * Tt) / 4, blk, 0, stream>>>(qbuf, kbuf, vbuf, obuf);

    gemm_f32<<<dim3(16, 64), blk, 0, stream>>>(obuf, Wo, out, 4096, 1024, 1024);
}

// Round 2
// 633.912 us; speedup vs baseline: 8.1769x; 8.1769x over previous
//
#include <hip/hip_runtime.h>

typedef __attribute__((ext_vector_type(8))) short short8;
typedef __attribute__((ext_vector_type(4))) float f32x4;

#define T_ 2048
#define H_ 16
#define KVH_ 4

__device__ inline unsigned short f2bf(float f) {
    unsigned u = __builtin_bit_cast(unsigned, f);
    u += 0x7fff + ((u >> 16) & 1);
    return (unsigned short)(u >> 16);
}

// ---------------------------------------------------------------------------
// Generic fp32 GEMM: C[M][N] = A[M][K] @ W[K][N].  64x64 tile, 4x4/thread.
// ---------------------------------------------------------------------------
__global__ __launch_bounds__(256) void gemm_f32(const float* __restrict__ A,
                                                const float* __restrict__ W,
                                                float* __restrict__ C,
                                                int M, int N, int K) {
    __shared__ float As[64][17];
    __shared__ float Bs[16][65];
    const int tid = threadIdx.x;
    const int tx = tid & 15, ty = tid >> 4;
    const int bx = blockIdx.x, by = blockIdx.y;
    float acc[4][4] = {};
    for (int k0 = 0; k0 < K; k0 += 16) {
        #pragma unroll
        for (int s = 0; s < 4; ++s) {
            int idx = tid + s * 256;
            int r = idx >> 4, kk = idx & 15;
            As[r][kk] = A[(size_t)(by * 64 + r) * K + k0 + kk];
        }
        #pragma unroll
        for (int s = 0; s < 4; ++s) {
            int idx = tid + s * 256;
            int kk = idx >> 6, c = idx & 63;
            Bs[kk][c] = W[(size_t)(k0 + kk) * N + bx * 64 + c];
        }
        __syncthreads();
        #pragma unroll
        for (int kk = 0; kk < 16; ++kk) {
            float a[4], b[4];
            #pragma unroll
            for (int i = 0; i < 4; ++i) a[i] = As[ty * 4 + i][kk];
            #pragma unroll
            for (int j = 0; j < 4; ++j) b[j] = Bs[kk][tx * 4 + j];
            #pragma unroll
            for (int i = 0; i < 4; ++i)
                #pragma unroll
                for (int j = 0; j < 4; ++j)
                    acc[i][j] += a[i] * b[j];
        }
        __syncthreads();
    }
    #pragma unroll
    for (int i = 0; i < 4; ++i) {
        size_t r = (size_t)(by * 64 + ty * 4 + i) * N + bx * 64 + tx * 4;
        #pragma unroll
        for (int j = 0; j < 4; ++j) C[r + j] = acc[i][j];
    }
}

// ---------------------------------------------------------------------------
// RoPE + scale + bf16 pack:  in [B*T][nh][64] f32  ->  out [B][nh][T][64] bf16
// ---------------------------------------------------------------------------
__global__ void pack_rope(const float* __restrict__ in,
                          const float* __restrict__ cosb,
                          const float* __restrict__ sinb,
                          unsigned short* __restrict__ outb,
                          int nh, float scale, int total) {
    int i = blockIdx.x * blockDim.x + threadIdx.x;
    if (i >= total) return;
    int d = i & 31;
    int rem = i >> 5;
    int h = rem % nh;
    int bt = rem / nh;
    int t = bt % T_;
    int b = bt / T_;
    float c = cosb[t * 32 + d];
    float s = sinb[t * 32 + d];
    const float* p = in + ((size_t)bt * nh + h) * 64;
    float x1 = p[d], x2 = p[d + 32];
    size_t o = (((size_t)(b * nh + h)) * T_ + t) * 64;
    outb[o + d]      = f2bf((x1 * c - x2 * s) * scale);
    outb[o + d + 32] = f2bf((x2 * c + x1 * s) * scale);
}

// ---------------------------------------------------------------------------
// V pack + transpose: in [B*T][4][64] f32 -> out [B][4][64][T] bf16
// ---------------------------------------------------------------------------
__global__ __launch_bounds__(256) void pack_vt(const float* __restrict__ in,
                                               unsigned short* __restrict__ outb) {
    __shared__ unsigned short ts[64][65];
    int bid = blockIdx.x;                 // (b*4+kv)*32 + t-tile
    int tt = bid & 31;
    int bkv = bid >> 5;
    int kv = bkv & 3;
    int b = bkv >> 2;
    int i = threadIdx.x;
    #pragma unroll
    for (int s = 0; s < 16; ++s) {
        int idx = i + s * 256;
        int tl = idx >> 6, d = idx & 63;
        ts[tl][d] = f2bf(in[(((size_t)(b * T_ + tt * 64 + tl)) * 4 + kv) * 64 + d]);
    }
    __syncthreads();
    #pragma unroll
    for (int s = 0; s < 16; ++s) {
        int idx = i + s * 256;
        int d = idx >> 6, tl = idx & 63;
        outb[(((size_t)(b * 4 + kv)) * 64 + d) * T_ + tt * 64 + tl] = ts[tl][d];
    }
}

// ---------------------------------------------------------------------------
// Flash attention, bf16 MFMA 16x16x32.
// Block = (b,h,q-tile of 64). 4 waves x 16 q-rows. Double-buffered K/V LDS.
// ---------------------------------------------------------------------------
__global__ __launch_bounds__(256) void attn_mfma(
        const unsigned short* __restrict__ Q,   // [B][16][T][64] (pre-scaled)
        const unsigned short* __restrict__ K,   // [B][4][T][64]
        const unsigned short* __restrict__ Vt,  // [B][4][64][T]
        float* __restrict__ O) {                // [B*T][16][64]
    __shared__ __align__(16) unsigned short Ks[2][64][72];
    __shared__ __align__(16) unsigned short Vs[2][64][72];
    __shared__ __align__(16) unsigned short Pl[4][16][72];

    const int bid = blockIdx.x;
    const int qt = bid & 31;
    const int h  = (bid >> 5) & 15;
    const int b  = bid >> 9;
    const int kv = h >> 2;
    const int tid = threadIdx.x;
    const int w = tid >> 6, l = tid & 63;
    const int lk = l & 15, lg = l >> 4;

    const unsigned short* Kb = K + ((size_t)(b * 4 + kv)) * T_ * 64;
    const unsigned short* Vb = Vt + ((size_t)(b * 4 + kv)) * 64 * T_;

    // Q fragments (A operand), rows qt*64 + w*16 + lk, k = lg*8.. (+32)
    const unsigned short* Qb =
        Q + (((size_t)(b * 16 + h)) * T_ + qt * 64 + w * 16 + lk) * 64 + lg * 8;
    short8 af0 = *(const short8*)(Qb);
    short8 af1 = *(const short8*)(Qb + 32);

    f32x4 acc[4] = {{0,0,0,0},{0,0,0,0},{0,0,0,0},{0,0,0,0}};
    float m[4], lsum[4];
    #pragma unroll
    for (int r = 0; r < 4; ++r) { m[r] = -1e38f; lsum[r] = 0.f; }

    auto stage = [&](int buf, int kt) {
        #pragma unroll
        for (int s = 0; s < 2; ++s) {
            int c = tid + s * 256;
            int key = c >> 3, off = (c & 7) * 8;
            *(short8*)(&Ks[buf][key][off]) =
                *(const short8*)(Kb + ((size_t)(kt * 64 + key)) * 64 + off);
        }
        #pragma unroll
        for (int s = 0; s < 2; ++s) {
            int c = tid + s * 256;
            int d = c >> 3, off = (c & 7) * 8;
            *(short8*)(&Vs[buf][d][off]) =
                *(const short8*)(Vb + (size_t)d * T_ + kt * 64 + off);
        }
    };

    stage(0, 0);
    for (int kt = 0; kt <= qt; ++kt) {
        int cur = kt & 1;
        __syncthreads();                    // staging of buf[cur] complete
        if (kt < qt) stage(cur ^ 1, kt + 1);

        // S = Q K^T   (4 sub-tiles of 16 keys)
        float s4[4][4];
        #pragma unroll
        for (int nt = 0; nt < 4; ++nt) {
            short8 b0 = *(const short8*)(&Ks[cur][nt * 16 + lk][lg * 8]);
            short8 b1 = *(const short8*)(&Ks[cur][nt * 16 + lk][32 + lg * 8]);
            f32x4 cacc = {0, 0, 0, 0};
            cacc = __builtin_amdgcn_mfma_f32_16x16x32_bf16(af0, b0, cacc, 0, 0, 0);
            cacc = __builtin_amdgcn_mfma_f32_16x16x32_bf16(af1, b1, cacc, 0, 0, 0);
            #pragma unroll
            for (int r = 0; r < 4; ++r) s4[nt][r] = cacc[r];
        }
        // causal mask (diagonal tile only; earlier tiles fully visible)
        if (kt == qt) {
            int qloc = w * 16 + lg * 4;
            #pragma unroll
            for (int nt = 0; nt < 4; ++nt) {
                int kloc = nt * 16 + lk;
                #pragma unroll
                for (int r = 0; r < 4; ++r)
                    if (kloc > qloc + r) s4[nt][r] = -1e30f;
            }
        }
        // online softmax (row = q = lg*4+r, spread over 16 lanes = keys)
        #pragma unroll
        for (int r = 0; r < 4; ++r) {
            float rm = fmaxf(fmaxf(s4[0][r], s4[1][r]), fmaxf(s4[2][r], s4[3][r]));
            rm = fmaxf(rm, __shfl_xor(rm, 1));
            rm = fmaxf(rm, __shfl_xor(rm, 2));
            rm = fmaxf(rm, __shfl_xor(rm, 4));
            rm = fmaxf(rm, __shfl_xor(rm, 8));
            float nm = fmaxf(m[r], rm);
            float corr = __expf(m[r] - nm);
            float psum = 0.f;
            #pragma unroll
            for (int nt = 0; nt < 4; ++nt) {
                float p = __expf(s4[nt][r] - nm);
                s4[nt][r] = p;
                psum += p;
            }
            psum += __shfl_xor(psum, 1);
            psum += __shfl_xor(psum, 2);
            psum += __shfl_xor(psum, 4);
            psum += __shfl_xor(psum, 8);
            lsum[r] = lsum[r] * corr + psum;
            m[r] = nm;
            #pragma unroll
            for (int db = 0; db < 4; ++db) acc[db][r] *= corr;
        }
        // P -> LDS (bf16) for re-fragmenting
        #pragma unroll
        for (int nt = 0; nt < 4; ++nt)
            #pragma unroll
            for (int r = 0; r < 4; ++r)
                Pl[w][lg * 4 + r][nt * 16 + lk] = f2bf(s4[nt][r]);
        __syncthreads();                    // Pl visible; Ks[cur] reads done
        // O += P V
        #pragma unroll
        for (int kk = 0; kk < 2; ++kk) {
            short8 pa = *(const short8*)(&Pl[w][lk][kk * 32 + lg * 8]);
            #pragma unroll
            for (int db = 0; db < 4; ++db) {
                short8 vb = *(const short8*)(&Vs[cur][db * 16 + lk][kk * 32 + lg * 8]);
                acc[db] = __builtin_amdgcn_mfma_f32_16x16x32_bf16(pa, vb, acc[db], 0, 0, 0);
            }
        }
    }
    // write O[b*T + t][h][64]
    #pragma unroll
    for (int db = 0; db < 4; ++db)
        #pragma unroll
        for (int r = 0; r < 4; ++r) {
            int t = qt * 64 + w * 16 + lg * 4 + r;
            O[(((size_t)(b * T_ + t)) * 16 + h) * 64 + db * 16 + lk] =
                acc[db][r] / lsum[r];
        }
}

// ---------------------------------------------------------------------------
extern "C" void kernel_launch(void* const* d_in, const int* in_sizes, int n_in,
                              void* d_out, int out_size, void* d_ws, size_t ws_size,
                              hipStream_t stream) {
    const float* x  = (const float*)d_in[0];
    const float* rc = (const float*)d_in[1];
    const float* rs = (const float*)d_in[2];
    const float* Wq = (const float*)d_in[4];
    const float* Wk = (const float*)d_in[5];
    const float* Wv = (const float*)d_in[6];
    const float* Wo = (const float*)d_in[7];
    float* out = (float*)d_out;

    float* ws = (float*)d_ws;
    const size_t M1 = 1024 * 1024;
    float* qbuf = ws;                       // 4M f32 (reused as obuf later)
    float* kbuf = ws + 4 * M1;              // 1M f32
    float* vbuf = ws + 5 * M1;              // 1M f32
    unsigned short* Qbf = (unsigned short*)(ws + 6 * M1);   // 4M bf16
    unsigned short* Kbf = (unsigned short*)(ws + 8 * M1);   // 1M bf16
    unsigned short* Vtb = (unsigned short*)(ws + 8 * M1 + 512 * 1024); // 1M bf16
    float* obuf = qbuf;                     // alias: qbuf dead after pack

    dim3 blk(256);
    gemm_f32<<<dim3(16, 64), blk, 0, stream>>>(x, Wq, qbuf, 4096, 1024, 1024);
    gemm_f32<<<dim3(4, 64),  blk, 0, stream>>>(x, Wk, kbuf, 4096, 256, 1024);
    gemm_f32<<<dim3(4, 64),  blk, 0, stream>>>(x, Wv, vbuf, 4096, 256, 1024);

    pack_rope<<<(2 * T_ * H_ * 32) / 256, blk, 0, stream>>>(
        qbuf, rc, rs, Qbf, H_, 0.125f, 2 * T_ * H_ * 32);
    pack_rope<<<(2 * T_ * KVH_ * 32) / 256, blk, 0, stream>>>(
        kbuf, rc, rs, Kbf, KVH_, 1.0f, 2 * T_ * KVH_ * 32);
    pack_vt<<<2 * KVH_ * (T_ / 64), blk, 0, stream>>>(vbuf, Vtb);

    attn_mfma<<<2 * H_ * (T_ / 64), blk, 0, stream>>>(Qbf, Kbf, Vtb, obuf);

    gemm_f32<<<dim3(16, 64), blk, 0, stream>>>(obuf, Wo, out, 4096, 1024, 1024);
}

// Round 3
// 227.863 us; speedup vs baseline: 22.7479x; 2.7820x over previous
//
#include <hip/hip_runtime.h>

typedef __attribute__((ext_vector_type(8))) short short8;
typedef __attribute__((ext_vector_type(4))) short short4v;
typedef __attribute__((ext_vector_type(4))) float f32x4;

#define T_ 2048
#define H_ 16
#define KVH_ 4

__device__ inline unsigned short f2bf(float f) {
    unsigned u = __builtin_bit_cast(unsigned, f);
    u += 0x7fff + ((u >> 16) & 1);
    return (unsigned short)(u >> 16);
}

__device__ inline void gl_lds16(const unsigned short* g, unsigned short* lds) {
    __builtin_amdgcn_global_load_lds(
        (const __attribute__((address_space(1))) unsigned int*)g,
        (__attribute__((address_space(3))) unsigned int*)lds, 16, 0, 0);
}

// ---------------------------------------------------------------------------
// f32 -> bf16 straight cast (8 elems/thread)
// ---------------------------------------------------------------------------
__global__ void cast_bf16(const float* __restrict__ in,
                          unsigned short* __restrict__ out, int n8) {
    int i = blockIdx.x * blockDim.x + threadIdx.x;
    if (i >= n8) return;
    float4 v0 = ((const float4*)in)[i * 2];
    float4 v1 = ((const float4*)in)[i * 2 + 1];
    short8 o;
    o[0] = f2bf(v0.x); o[1] = f2bf(v0.y); o[2] = f2bf(v0.z); o[3] = f2bf(v0.w);
    o[4] = f2bf(v1.x); o[5] = f2bf(v1.y); o[6] = f2bf(v1.z); o[7] = f2bf(v1.w);
    ((short8*)out)[i] = o;
}

// ---------------------------------------------------------------------------
// W [K][N] f32  ->  out [rowoff + N][K] bf16   (transpose + cast), 64x64 tiles
// ---------------------------------------------------------------------------
__global__ __launch_bounds__(256) void transpose_cast(
        const float* __restrict__ W, unsigned short* __restrict__ out,
        int K, int N, int rowoff) {
    __shared__ unsigned short ts[64][66];
    const int bx = blockIdx.x, by = blockIdx.y, tid = threadIdx.x;
    #pragma unroll
    for (int s = 0; s < 16; ++s) {
        int idx = tid + s * 256;
        int kl = idx >> 6, nl = idx & 63;
        ts[kl][nl] = f2bf(W[(size_t)(by * 64 + kl) * N + bx * 64 + nl]);
    }
    __syncthreads();
    #pragma unroll
    for (int s = 0; s < 16; ++s) {
        int idx = tid + s * 256;
        int nl = idx >> 6, kl = idx & 63;
        out[(size_t)(rowoff + bx * 64 + nl) * K + by * 64 + kl] = ts[kl][nl];
    }
}

// ---------------------------------------------------------------------------
// bf16 MFMA GEMM, 128x128 tile, BK=32, global_load_lds staging.
// A [M][K] bf16, Bt [N][K] bf16 (pre-transposed).
// MODE 0: C = f32 [M][N]
// MODE 1: Q path — RoPE + scale, write bf16 [B][16][T][64]
// MODE 2: KV path (N=512) — cols<256: K RoPE -> bf16 [B][4][T][64];
//                           cols>=256: V -> bf16 [B][4][64][T] (transposed)
// ---------------------------------------------------------------------------
template <int MODE>
__global__ __launch_bounds__(256) void gemm_mfma(
        const unsigned short* __restrict__ A,
        const unsigned short* __restrict__ Bt,
        void* __restrict__ Cv, unsigned short* __restrict__ C2,
        const float* __restrict__ rc, const float* __restrict__ rs,
        int M, int N, int K, float scale) {
    __shared__ __align__(16) unsigned short As[128 * 32];
    __shared__ __align__(16) unsigned short Bs[128 * 32];
    const int tid = threadIdx.x;
    const int w = tid >> 6, l = tid & 63, lk = l & 15, lg = l >> 4;
    const int wr = w >> 1, wc = w & 1;
    const int bx = blockIdx.x, by = blockIdx.y;

    const unsigned short* Arow = A + (size_t)by * 128 * K;
    const unsigned short* Brow = Bt + (size_t)bx * 128 * K;

    f32x4 acc[4][4];
    #pragma unroll
    for (int m = 0; m < 4; ++m)
        #pragma unroll
        for (int n = 0; n < 4; ++n) acc[m][n] = (f32x4){0, 0, 0, 0};

    for (int k0 = 0; k0 < K; k0 += 32) {
        #pragma unroll
        for (int p = 0; p < 2; ++p) {
            int cb = w * 64 + p * 256;          // wave-uniform chunk base
            int c = cb + l;
            int row = c >> 2, ko = (c & 3) * 8;
            gl_lds16(Arow + (size_t)row * K + k0 + ko, As + cb * 8);
            gl_lds16(Brow + (size_t)row * K + k0 + ko, Bs + cb * 8);
        }
        __syncthreads();
        short8 aF[4], bF[4];
        #pragma unroll
        for (int m = 0; m < 4; ++m)
            aF[m] = *(const short8*)&As[(wr * 64 + m * 16 + lk) * 32 + lg * 8];
        #pragma unroll
        for (int n = 0; n < 4; ++n)
            bF[n] = *(const short8*)&Bs[(wc * 64 + n * 16 + lk) * 32 + lg * 8];
        #pragma unroll
        for (int m = 0; m < 4; ++m)
            #pragma unroll
            for (int n = 0; n < 4; ++n)
                acc[m][n] = __builtin_amdgcn_mfma_f32_16x16x32_bf16(
                    aF[m], bF[n], acc[m][n], 0, 0, 0);
        __syncthreads();
    }

    const int rowbase = by * 128 + wr * 64;
    if constexpr (MODE == 0) {
        float* C = (float*)Cv;
        #pragma unroll
        for (int m = 0; m < 4; ++m)
            #pragma unroll
            for (int r = 0; r < 4; ++r) {
                size_t ro = (size_t)(rowbase + m * 16 + lg * 4 + r) * N +
                            bx * 128 + wc * 64 + lk;
                #pragma unroll
                for (int n = 0; n < 4; ++n) C[ro + n * 16] = acc[m][n][r];
            }
    }
    if constexpr (MODE == 1) {
        unsigned short* C = (unsigned short*)Cv;
        const int h = bx * 2 + wc;
        #pragma unroll
        for (int m = 0; m < 4; ++m)
            #pragma unroll
            for (int r = 0; r < 4; ++r) {
                int trow = rowbase + m * 16 + lg * 4 + r;
                int b = trow >> 11, t = trow & (T_ - 1);
                size_t ob = (((size_t)(b * 16 + h)) * T_ + t) * 64;
                #pragma unroll
                for (int n = 0; n < 2; ++n) {
                    int d = n * 16 + lk;
                    float cc = rc[t * 32 + d], ss = rs[t * 32 + d];
                    float x1 = acc[m][n][r], x2 = acc[m][n + 2][r];
                    C[ob + d]      = f2bf((x1 * cc - x2 * ss) * scale);
                    C[ob + d + 32] = f2bf((x2 * cc + x1 * ss) * scale);
                }
            }
    }
    if constexpr (MODE == 2) {
        const int colblk = bx * 2 + wc;        // 64-col group, 0..7
        if (colblk < 4) {                      // K heads, RoPE, scale=1
            unsigned short* C = (unsigned short*)Cv;
            const int kvh = colblk;
            #pragma unroll
            for (int m = 0; m < 4; ++m)
                #pragma unroll
                for (int r = 0; r < 4; ++r) {
                    int trow = rowbase + m * 16 + lg * 4 + r;
                    int b = trow >> 11, t = trow & (T_ - 1);
                    size_t ob = (((size_t)(b * 4 + kvh)) * T_ + t) * 64;
                    #pragma unroll
                    for (int n = 0; n < 2; ++n) {
                        int d = n * 16 + lk;
                        float cc = rc[t * 32 + d], ss = rs[t * 32 + d];
                        float x1 = acc[m][n][r], x2 = acc[m][n + 2][r];
                        C[ob + d]      = f2bf(x1 * cc - x2 * ss);
                        C[ob + d + 32] = f2bf(x2 * cc + x1 * ss);
                    }
                }
        } else {                               // V heads -> transposed layout
            const int kvh = colblk - 4;
            #pragma unroll
            for (int m = 0; m < 4; ++m) {
                int trow0 = rowbase + m * 16 + lg * 4;
                int b = trow0 >> 11, t0 = trow0 & (T_ - 1);
                #pragma unroll
                for (int n = 0; n < 4; ++n) {
                    int d = n * 16 + lk;
                    short4v pk;
                    #pragma unroll
                    for (int r = 0; r < 4; ++r) pk[r] = f2bf(acc[m][n][r]);
                    *(short4v*)(C2 + (((size_t)(b * 4 + kvh)) * 64 + d) * T_ + t0) = pk;
                }
            }
        }
    }
}

// ---------------------------------------------------------------------------
// Flash attention, bf16 MFMA 16x16x32 (unchanged core; O written as bf16)
// ---------------------------------------------------------------------------
__global__ __launch_bounds__(256) void attn_mfma(
        const unsigned short* __restrict__ Q,   // [B][16][T][64] (pre-scaled)
        const unsigned short* __restrict__ K,   // [B][4][T][64]
        const unsigned short* __restrict__ Vt,  // [B][4][64][T]
        unsigned short* __restrict__ O) {       // [B*T][16][64] bf16
    __shared__ __align__(16) unsigned short Ks[2][64][72];
    __shared__ __align__(16) unsigned short Vs[2][64][72];
    __shared__ __align__(16) unsigned short Pl[4][16][72];

    const int bid = blockIdx.x;
    const int qt = bid & 31;
    const int h  = (bid >> 5) & 15;
    const int b  = bid >> 9;
    const int kv = h >> 2;
    const int tid = threadIdx.x;
    const int w = tid >> 6, l = tid & 63;
    const int lk = l & 15, lg = l >> 4;

    const unsigned short* Kb = K + ((size_t)(b * 4 + kv)) * T_ * 64;
    const unsigned short* Vb = Vt + ((size_t)(b * 4 + kv)) * 64 * T_;

    const unsigned short* Qb =
        Q + (((size_t)(b * 16 + h)) * T_ + qt * 64 + w * 16 + lk) * 64 + lg * 8;
    short8 af0 = *(const short8*)(Qb);
    short8 af1 = *(const short8*)(Qb + 32);

    f32x4 acc[4] = {{0,0,0,0},{0,0,0,0},{0,0,0,0},{0,0,0,0}};
    float m[4], lsum[4];
    #pragma unroll
    for (int r = 0; r < 4; ++r) { m[r] = -1e38f; lsum[r] = 0.f; }

    auto stage = [&](int buf, int kt) {
        #pragma unroll
        for (int s = 0; s < 2; ++s) {
            int c = tid + s * 256;
            int key = c >> 3, off = (c & 7) * 8;
            *(short8*)(&Ks[buf][key][off]) =
                *(const short8*)(Kb + ((size_t)(kt * 64 + key)) * 64 + off);
        }
        #pragma unroll
        for (int s = 0; s < 2; ++s) {
            int c = tid + s * 256;
            int d = c >> 3, off = (c & 7) * 8;
            *(short8*)(&Vs[buf][d][off]) =
                *(const short8*)(Vb + (size_t)d * T_ + kt * 64 + off);
        }
    };

    stage(0, 0);
    for (int kt = 0; kt <= qt; ++kt) {
        int cur = kt & 1;
        __syncthreads();
        if (kt < qt) stage(cur ^ 1, kt + 1);

        float s4[4][4];
        #pragma unroll
        for (int nt = 0; nt < 4; ++nt) {
            short8 b0 = *(const short8*)(&Ks[cur][nt * 16 + lk][lg * 8]);
            short8 b1 = *(const short8*)(&Ks[cur][nt * 16 + lk][32 + lg * 8]);
            f32x4 cacc = {0, 0, 0, 0};
            cacc = __builtin_amdgcn_mfma_f32_16x16x32_bf16(af0, b0, cacc, 0, 0, 0);
            cacc = __builtin_amdgcn_mfma_f32_16x16x32_bf16(af1, b1, cacc, 0, 0, 0);
            #pragma unroll
            for (int r = 0; r < 4; ++r) s4[nt][r] = cacc[r];
        }
        if (kt == qt) {
            int qloc = w * 16 + lg * 4;
            #pragma unroll
            for (int nt = 0; nt < 4; ++nt) {
                int kloc = nt * 16 + lk;
                #pragma unroll
                for (int r = 0; r < 4; ++r)
                    if (kloc > qloc + r) s4[nt][r] = -1e30f;
            }
        }
        #pragma unroll
        for (int r = 0; r < 4; ++r) {
            float rm = fmaxf(fmaxf(s4[0][r], s4[1][r]), fmaxf(s4[2][r], s4[3][r]));
            rm = fmaxf(rm, __shfl_xor(rm, 1));
            rm = fmaxf(rm, __shfl_xor(rm, 2));
            rm = fmaxf(rm, __shfl_xor(rm, 4));
            rm = fmaxf(rm, __shfl_xor(rm, 8));
            float nm = fmaxf(m[r], rm);
            float corr = __expf(m[r] - nm);
            float psum = 0.f;
            #pragma unroll
            for (int nt = 0; nt < 4; ++nt) {
                float p = __expf(s4[nt][r] - nm);
                s4[nt][r] = p;
                psum += p;
            }
            psum += __shfl_xor(psum, 1);
            psum += __shfl_xor(psum, 2);
            psum += __shfl_xor(psum, 4);
            psum += __shfl_xor(psum, 8);
            lsum[r] = lsum[r] * corr + psum;
            m[r] = nm;
            #pragma unroll
            for (int db = 0; db < 4; ++db) acc[db][r] *= corr;
        }
        #pragma unroll
        for (int nt = 0; nt < 4; ++nt)
            #pragma unroll
            for (int r = 0; r < 4; ++r)
                Pl[w][lg * 4 + r][nt * 16 + lk] = f2bf(s4[nt][r]);
        __syncthreads();
        #pragma unroll
        for (int kk = 0; kk < 2; ++kk) {
            short8 pa = *(const short8*)(&Pl[w][lk][kk * 32 + lg * 8]);
            #pragma unroll
            for (int db = 0; db < 4; ++db) {
                short8 vb = *(const short8*)(&Vs[cur][db * 16 + lk][kk * 32 + lg * 8]);
                acc[db] = __builtin_amdgcn_mfma_f32_16x16x32_bf16(pa, vb, acc[db], 0, 0, 0);
            }
        }
    }
    #pragma unroll
    for (int db = 0; db < 4; ++db)
        #pragma unroll
        for (int r = 0; r < 4; ++r) {
            int t = qt * 64 + w * 16 + lg * 4 + r;
            O[(((size_t)(b * T_ + t)) * 16 + h) * 64 + db * 16 + lk] =
                f2bf(acc[db][r] / lsum[r]);
        }
}

// ---------------------------------------------------------------------------
extern "C" void kernel_launch(void* const* d_in, const int* in_sizes, int n_in,
                              void* d_out, int out_size, void* d_ws, size_t ws_size,
                              hipStream_t stream) {
    const float* x  = (const float*)d_in[0];
    const float* rc = (const float*)d_in[1];
    const float* rs = (const float*)d_in[2];
    const float* Wq = (const float*)d_in[4];
    const float* Wk = (const float*)d_in[5];
    const float* Wv = (const float*)d_in[6];
    const float* Wo = (const float*)d_in[7];
    float* out = (float*)d_out;

    unsigned short* ws = (unsigned short*)d_ws;
    const size_t M1 = 1024 * 1024;
    unsigned short* xb   = ws;                 // 4M
    unsigned short* Wqt  = ws + 4 * M1;        // 1M
    unsigned short* Wkvt = ws + 5 * M1;        // 512K
    unsigned short* Wot  = ws + 5 * M1 + 512 * 1024;   // 1M
    unsigned short* Qbf  = ws + 6 * M1 + 512 * 1024;   // 4M
    unsigned short* Kbf  = ws + 10 * M1 + 512 * 1024;  // 1M
    unsigned short* Vtb  = ws + 11 * M1 + 512 * 1024;  // 1M
    unsigned short* Ob   = ws + 12 * M1 + 512 * 1024;  // 4M

    dim3 blk(256);
    cast_bf16<<<2048, blk, 0, stream>>>(x, xb, 4 * M1 / 8);
    transpose_cast<<<dim3(16, 16), blk, 0, stream>>>(Wq, Wqt, 1024, 1024, 0);
    transpose_cast<<<dim3(4, 16),  blk, 0, stream>>>(Wk, Wkvt, 1024, 256, 0);
    transpose_cast<<<dim3(4, 16),  blk, 0, stream>>>(Wv, Wkvt, 1024, 256, 256);
    transpose_cast<<<dim3(16, 16), blk, 0, stream>>>(Wo, Wot, 1024, 1024, 0);

    gemm_mfma<1><<<dim3(8, 32), blk, 0, stream>>>(
        xb, Wqt, (void*)Qbf, nullptr, rc, rs, 4096, 1024, 1024, 0.125f);
    gemm_mfma<2><<<dim3(4, 32), blk, 0, stream>>>(
        xb, Wkvt, (void*)Kbf, Vtb, rc, rs, 4096, 512, 1024, 1.0f);

    attn_mfma<<<2 * H_ * (T_ / 64), blk, 0, stream>>>(Qbf, Kbf, Vtb, Ob);

    gemm_mfma<0><<<dim3(8, 32), blk, 0, stream>>>(
        Ob, Wot, (void*)out, nullptr, nullptr, nullptr, 4096, 1024, 1024, 1.0f);
}

// Round 4
// 163.501 us; speedup vs baseline: 31.7027x; 1.3937x over previous
//
#include <hip/hip_runtime.h>

typedef __attribute__((ext_vector_type(8))) short short8;
typedef __attribute__((ext_vector_type(4))) short short4v;
typedef __attribute__((ext_vector_type(4))) float f32x4;

#define T_ 2048
#define H_ 16
#define KVH_ 4

__device__ inline unsigned short f2bf(float f) {
    unsigned u = __builtin_bit_cast(unsigned, f);
    u += 0x7fff + ((u >> 16) & 1);
    return (unsigned short)(u >> 16);
}

__device__ inline void gl_lds16(const unsigned short* g, unsigned short* lds) {
    __builtin_amdgcn_global_load_lds(
        (const __attribute__((address_space(1))) unsigned int*)g,
        (__attribute__((address_space(3))) unsigned int*)lds, 16, 0, 0);
}

// ---------------------------------------------------------------------------
// f32 -> bf16 straight cast (8 elems/thread)
// ---------------------------------------------------------------------------
__global__ void cast_bf16(const float* __restrict__ in,
                          unsigned short* __restrict__ out, int n8) {
    int i = blockIdx.x * blockDim.x + threadIdx.x;
    if (i >= n8) return;
    float4 v0 = ((const float4*)in)[i * 2];
    float4 v1 = ((const float4*)in)[i * 2 + 1];
    short8 o;
    o[0] = f2bf(v0.x); o[1] = f2bf(v0.y); o[2] = f2bf(v0.z); o[3] = f2bf(v0.w);
    o[4] = f2bf(v1.x); o[5] = f2bf(v1.y); o[6] = f2bf(v1.z); o[7] = f2bf(v1.w);
    ((short8*)out)[i] = o;
}

// ---------------------------------------------------------------------------
// W [K][N] f32  ->  out [rowoff + N][K] bf16   (transpose + cast), 64x64 tiles
// ---------------------------------------------------------------------------
__global__ __launch_bounds__(256) void transpose_cast(
        const float* __restrict__ W, unsigned short* __restrict__ out,
        int K, int N, int rowoff) {
    __shared__ unsigned short ts[64][66];
    const int bx = blockIdx.x, by = blockIdx.y, tid = threadIdx.x;
    #pragma unroll
    for (int s = 0; s < 16; ++s) {
        int idx = tid + s * 256;
        int kl = idx >> 6, nl = idx & 63;
        ts[kl][nl] = f2bf(W[(size_t)(by * 64 + kl) * N + bx * 64 + nl]);
    }
    __syncthreads();
    #pragma unroll
    for (int s = 0; s < 16; ++s) {
        int idx = tid + s * 256;
        int nl = idx >> 6, kl = idx & 63;
        out[(size_t)(rowoff + bx * 64 + nl) * K + by * 64 + kl] = ts[kl][nl];
    }
}

// ---------------------------------------------------------------------------
// bf16 MFMA GEMM, 128x128 tile, BK=32, global_load_lds staging.
// ---------------------------------------------------------------------------
template <int MODE>
__global__ __launch_bounds__(256) void gemm_mfma(
        const unsigned short* __restrict__ A,
        const unsigned short* __restrict__ Bt,
        void* __restrict__ Cv, unsigned short* __restrict__ C2,
        const float* __restrict__ rc, const float* __restrict__ rs,
        int M, int N, int K, float scale) {
    __shared__ __align__(16) unsigned short As[128 * 32];
    __shared__ __align__(16) unsigned short Bs[128 * 32];
    const int tid = threadIdx.x;
    const int w = tid >> 6, l = tid & 63, lk = l & 15, lg = l >> 4;
    const int wr = w >> 1, wc = w & 1;
    const int bx = blockIdx.x, by = blockIdx.y;

    const unsigned short* Arow = A + (size_t)by * 128 * K;
    const unsigned short* Brow = Bt + (size_t)bx * 128 * K;

    f32x4 acc[4][4];
    #pragma unroll
    for (int m = 0; m < 4; ++m)
        #pragma unroll
        for (int n = 0; n < 4; ++n) acc[m][n] = (f32x4){0, 0, 0, 0};

    for (int k0 = 0; k0 < K; k0 += 32) {
        #pragma unroll
        for (int p = 0; p < 2; ++p) {
            int cb = w * 64 + p * 256;
            int c = cb + l;
            int row = c >> 2, ko = (c & 3) * 8;
            gl_lds16(Arow + (size_t)row * K + k0 + ko, As + cb * 8);
            gl_lds16(Brow + (size_t)row * K + k0 + ko, Bs + cb * 8);
        }
        __syncthreads();
        short8 aF[4], bF[4];
        #pragma unroll
        for (int m = 0; m < 4; ++m)
            aF[m] = *(const short8*)&As[(wr * 64 + m * 16 + lk) * 32 + lg * 8];
        #pragma unroll
        for (int n = 0; n < 4; ++n)
            bF[n] = *(const short8*)&Bs[(wc * 64 + n * 16 + lk) * 32 + lg * 8];
        #pragma unroll
        for (int m = 0; m < 4; ++m)
            #pragma unroll
            for (int n = 0; n < 4; ++n)
                acc[m][n] = __builtin_amdgcn_mfma_f32_16x16x32_bf16(
                    aF[m], bF[n], acc[m][n], 0, 0, 0);
        __syncthreads();
    }

    const int rowbase = by * 128 + wr * 64;
    if constexpr (MODE == 0) {
        float* C = (float*)Cv;
        #pragma unroll
        for (int m = 0; m < 4; ++m)
            #pragma unroll
            for (int r = 0; r < 4; ++r) {
                size_t ro = (size_t)(rowbase + m * 16 + lg * 4 + r) * N +
                            bx * 128 + wc * 64 + lk;
                #pragma unroll
                for (int n = 0; n < 4; ++n) C[ro + n * 16] = acc[m][n][r];
            }
    }
    if constexpr (MODE == 1) {
        unsigned short* C = (unsigned short*)Cv;
        const int h = bx * 2 + wc;
        #pragma unroll
        for (int m = 0; m < 4; ++m)
            #pragma unroll
            for (int r = 0; r < 4; ++r) {
                int trow = rowbase + m * 16 + lg * 4 + r;
                int b = trow >> 11, t = trow & (T_ - 1);
                size_t ob = (((size_t)(b * 16 + h)) * T_ + t) * 64;
                #pragma unroll
                for (int n = 0; n < 2; ++n) {
                    int d = n * 16 + lk;
                    float cc = rc[t * 32 + d], ss = rs[t * 32 + d];
                    float x1 = acc[m][n][r], x2 = acc[m][n + 2][r];
                    C[ob + d]      = f2bf((x1 * cc - x2 * ss) * scale);
                    C[ob + d + 32] = f2bf((x2 * cc + x1 * ss) * scale);
                }
            }
    }
    if constexpr (MODE == 2) {
        const int colblk = bx * 2 + wc;
        if (colblk < 4) {
            unsigned short* C = (unsigned short*)Cv;
            const int kvh = colblk;
            #pragma unroll
            for (int m = 0; m < 4; ++m)
                #pragma unroll
                for (int r = 0; r < 4; ++r) {
                    int trow = rowbase + m * 16 + lg * 4 + r;
                    int b = trow >> 11, t = trow & (T_ - 1);
                    size_t ob = (((size_t)(b * 4 + kvh)) * T_ + t) * 64;
                    #pragma unroll
                    for (int n = 0; n < 2; ++n) {
                        int d = n * 16 + lk;
                        float cc = rc[t * 32 + d], ss = rs[t * 32 + d];
                        float x1 = acc[m][n][r], x2 = acc[m][n + 2][r];
                        C[ob + d]      = f2bf(x1 * cc - x2 * ss);
                        C[ob + d + 32] = f2bf(x2 * cc + x1 * ss);
                    }
                }
        } else {
            const int kvh = colblk - 4;
            #pragma unroll
            for (int m = 0; m < 4; ++m) {
                int trow0 = rowbase + m * 16 + lg * 4;
                int b = trow0 >> 11, t0 = trow0 & (T_ - 1);
                #pragma unroll
                for (int n = 0; n < 4; ++n) {
                    int d = n * 16 + lk;
                    short4v pk;
                    #pragma unroll
                    for (int r = 0; r < 4; ++r) pk[r] = f2bf(acc[m][n][r]);
                    *(short4v*)(C2 + (((size_t)(b * 4 + kvh)) * 64 + d) * T_ + t0) = pk;
                }
            }
        }
    }
}

// ---------------------------------------------------------------------------
// Flash attention v2: paired q-tiles (j, 31-j) per block -> constant work.
// 4 waves x 16 q-rows per tile. One barrier/iter. lsum via MFMA ones-trick.
// ---------------------------------------------------------------------------
__global__ __launch_bounds__(256) void attn_mfma(
        const unsigned short* __restrict__ Q,   // [B][16][T][64] (pre-scaled)
        const unsigned short* __restrict__ K,   // [B][4][T][64]
        const unsigned short* __restrict__ Vt,  // [B][4][64][T]
        unsigned short* __restrict__ O) {       // [B*T][16][64] bf16
    __shared__ __align__(16) unsigned short Ks[2][64][68];
    __shared__ __align__(16) unsigned short Vs[2][64][68];
    __shared__ __align__(16) unsigned short Pl[4][16][68];

    const int bid = blockIdx.x;
    const int jp = bid & 15;
    const int h  = (bid >> 4) & 15;
    const int b  = bid >> 8;
    const int kv = h >> 2;
    const int qt0 = jp;          // short tile
    const int qt1 = 31 - jp;     // long tile
    const int tid = threadIdx.x;
    const int w = tid >> 6, l = tid & 63;
    const int lk = l & 15, lg = l >> 4;

    const unsigned short* Kb = K + ((size_t)(b * 4 + kv)) * T_ * 64;
    const unsigned short* Vb = Vt + ((size_t)(b * 4 + kv)) * 64 * T_;

    short8 af[2][2];
    {
        const unsigned short* q0 =
            Q + (((size_t)(b * 16 + h)) * T_ + qt0 * 64 + w * 16 + lk) * 64 + lg * 8;
        af[0][0] = *(const short8*)(q0);
        af[0][1] = *(const short8*)(q0 + 32);
        const unsigned short* q1 =
            Q + (((size_t)(b * 16 + h)) * T_ + qt1 * 64 + w * 16 + lk) * 64 + lg * 8;
        af[1][0] = *(const short8*)(q1);
        af[1][1] = *(const short8*)(q1 + 32);
    }

    f32x4 acc[2][4];
    f32x4 lacc[2];
    float mrow[2][4];
    #pragma unroll
    for (int ti = 0; ti < 2; ++ti) {
        lacc[ti] = (f32x4){0, 0, 0, 0};
        #pragma unroll
        for (int db = 0; db < 4; ++db) acc[ti][db] = (f32x4){0, 0, 0, 0};
        #pragma unroll
        for (int r = 0; r < 4; ++r) mrow[ti][r] = -1e38f;
    }

    short8 ones;
    #pragma unroll
    for (int i = 0; i < 8; ++i) ones[i] = (short)0x3F80;   // bf16 1.0

    const int srow = tid >> 2;            // 0..63
    const int soff = (tid & 3) * 16;      // 0,16,32,48

    short8 kr0, kr1, vr0, vr1;
    auto load_kv = [&](int kt) {
        const unsigned short* kg = Kb + ((size_t)(kt * 64 + srow)) * 64 + soff;
        kr0 = *(const short8*)(kg);
        kr1 = *(const short8*)(kg + 8);
        const unsigned short* vg = Vb + (size_t)srow * T_ + kt * 64 + soff;
        vr0 = *(const short8*)(vg);
        vr1 = *(const short8*)(vg + 8);
    };
    auto write_kv = [&](int buf) {
        *(short8*)(&Ks[buf][srow][soff])     = kr0;
        *(short8*)(&Ks[buf][srow][soff + 8]) = kr1;
        *(short8*)(&Vs[buf][srow][soff])     = vr0;
        *(short8*)(&Vs[buf][srow][soff + 8]) = vr1;
    };

    // score: QK^T + mask + online softmax + Pl write (wave-local)
    auto score = [&](int ti, int qt, int kt, int cur) {
        float s4[4][4];
        __builtin_amdgcn_s_setprio(1);
        #pragma unroll
        for (int nt = 0; nt < 4; ++nt) {
            short8 b0 = *(const short8*)(&Ks[cur][nt * 16 + lk][lg * 8]);
            short8 b1 = *(const short8*)(&Ks[cur][nt * 16 + lk][32 + lg * 8]);
            f32x4 c = {0, 0, 0, 0};
            c = __builtin_amdgcn_mfma_f32_16x16x32_bf16(af[ti][0], b0, c, 0, 0, 0);
            c = __builtin_amdgcn_mfma_f32_16x16x32_bf16(af[ti][1], b1, c, 0, 0, 0);
            #pragma unroll
            for (int r = 0; r < 4; ++r) s4[nt][r] = c[r];
        }
        __builtin_amdgcn_s_setprio(0);
        if (kt == qt) {
            int qloc = w * 16 + lg * 4;
            #pragma unroll
            for (int nt = 0; nt < 4; ++nt) {
                int kloc = nt * 16 + lk;
                #pragma unroll
                for (int r = 0; r < 4; ++r)
                    if (kloc > qloc + r) s4[nt][r] = -1e30f;
            }
        }
        #pragma unroll
        for (int r = 0; r < 4; ++r) {
            float rm = fmaxf(fmaxf(s4[0][r], s4[1][r]), fmaxf(s4[2][r], s4[3][r]));
            rm = fmaxf(rm, __shfl_xor(rm, 1));
            rm = fmaxf(rm, __shfl_xor(rm, 2));
            rm = fmaxf(rm, __shfl_xor(rm, 4));
            rm = fmaxf(rm, __shfl_xor(rm, 8));
            float nm = fmaxf(mrow[ti][r], rm);
            float corr = __expf(mrow[ti][r] - nm);
            mrow[ti][r] = nm;
            #pragma unroll
            for (int nt = 0; nt < 4; ++nt) s4[nt][r] = __expf(s4[nt][r] - nm);
            #pragma unroll
            for (int db = 0; db < 4; ++db) acc[ti][db][r] *= corr;
            lacc[ti][r] *= corr;
        }
        #pragma unroll
        for (int nt = 0; nt < 4; ++nt)
            #pragma unroll
            for (int r = 0; r < 4; ++r)
                Pl[w][lg * 4 + r][nt * 16 + lk] = f2bf(s4[nt][r]);
    };
    // pv: O += P V; lsum += P 1  (reads Pl written by same wave)
    auto pv = [&](int ti, int cur) {
        __builtin_amdgcn_s_setprio(1);
        #pragma unroll
        for (int kk = 0; kk < 2; ++kk) {
            short8 pa = *(const short8*)(&Pl[w][lk][kk * 32 + lg * 8]);
            lacc[ti] = __builtin_amdgcn_mfma_f32_16x16x32_bf16(pa, ones, lacc[ti], 0, 0, 0);
            #pragma unroll
            for (int db = 0; db < 4; ++db) {
                short8 vb = *(const short8*)(&Vs[cur][db * 16 + lk][kk * 32 + lg * 8]);
                acc[ti][db] = __builtin_amdgcn_mfma_f32_16x16x32_bf16(pa, vb, acc[ti][db], 0, 0, 0);
            }
        }
        __builtin_amdgcn_s_setprio(0);
    };

    load_kv(0);
    write_kv(0);
    for (int kt = 0; kt <= qt1; ++kt) {
        const int cur = kt & 1;
        __syncthreads();                        // staging of buf[cur] visible
        const bool pf = kt < qt1;
        if (pf) load_kv(kt + 1);                // issue early (T14)
        if (kt <= qt0) { score(0, qt0, kt, cur); pv(0, cur); }
        score(1, qt1, kt, cur);
        if (pf) write_kv(cur ^ 1);              // write late, covered by compute
        pv(1, cur);
    }

    #pragma unroll
    for (int ti = 0; ti < 2; ++ti) {
        const int qt = ti ? qt1 : qt0;
        #pragma unroll
        for (int r = 0; r < 4; ++r) {
            float inv = 1.f / lacc[ti][r];
            int t = qt * 64 + w * 16 + lg * 4 + r;
            #pragma unroll
            for (int db = 0; db < 4; ++db)
                O[(((size_t)(b * T_ + t)) * 16 + h) * 64 + db * 16 + lk] =
                    f2bf(acc[ti][db][r] * inv);
        }
    }
}

// ---------------------------------------------------------------------------
extern "C" void kernel_launch(void* const* d_in, const int* in_sizes, int n_in,
                              void* d_out, int out_size, void* d_ws, size_t ws_size,
                              hipStream_t stream) {
    const float* x  = (const float*)d_in[0];
    const float* rc = (const float*)d_in[1];
    const float* rs = (const float*)d_in[2];
    const float* Wq = (const float*)d_in[4];
    const float* Wk = (const float*)d_in[5];
    const float* Wv = (const float*)d_in[6];
    const float* Wo = (const float*)d_in[7];
    float* out = (float*)d_out;

    unsigned short* ws = (unsigned short*)d_ws;
    const size_t M1 = 1024 * 1024;
    unsigned short* xb   = ws;
    unsigned short* Wqt  = ws + 4 * M1;
    unsigned short* Wkvt = ws + 5 * M1;
    unsigned short* Wot  = ws + 5 * M1 + 512 * 1024;
    unsigned short* Qbf  = ws + 6 * M1 + 512 * 1024;
    unsigned short* Kbf  = ws + 10 * M1 + 512 * 1024;
    unsigned short* Vtb  = ws + 11 * M1 + 512 * 1024;
    unsigned short* Ob   = ws + 12 * M1 + 512 * 1024;

    dim3 blk(256);
    cast_bf16<<<2048, blk, 0, stream>>>(x, xb, 4 * M1 / 8);
    transpose_cast<<<dim3(16, 16), blk, 0, stream>>>(Wq, Wqt, 1024, 1024, 0);
    transpose_cast<<<dim3(4, 16),  blk, 0, stream>>>(Wk, Wkvt, 1024, 256, 0);
    transpose_cast<<<dim3(4, 16),  blk, 0, stream>>>(Wv, Wkvt, 1024, 256, 256);
    transpose_cast<<<dim3(16, 16), blk, 0, stream>>>(Wo, Wot, 1024, 1024, 0);

    gemm_mfma<1><<<dim3(8, 32), blk, 0, stream>>>(
        xb, Wqt, (void*)Qbf, nullptr, rc, rs, 4096, 1024, 1024, 0.125f);
    gemm_mfma<2><<<dim3(4, 32), blk, 0, stream>>>(
        xb, Wkvt, (void*)Kbf, Vtb, rc, rs, 4096, 512, 1024, 1.0f);

    attn_mfma<<<dim3(2 * H_ * 16), blk, 0, stream>>>(Qbf, Kbf, Vtb, Ob);

    gemm_mfma<0><<<dim3(8, 32), blk, 0, stream>>>(
        Ob, Wot, (void*)out, nullptr, nullptr, nullptr, 4096, 1024, 1024, 1.0f);
}

// Round 5
// 144.554 us; speedup vs baseline: 35.8579x; 1.1311x over previous
//
#include <hip/hip_runtime.h>

typedef __attribute__((ext_vector_type(8))) short short8;
typedef __attribute__((ext_vector_type(4))) short short4v;
typedef __attribute__((ext_vector_type(4))) float f32x4;

#define T_ 2048
#define H_ 16
#define KVH_ 4
#define QSCALE 0.18033688011112042f   // 0.125 * log2(e): softmax in base-2 domain

__device__ inline unsigned short f2bf(float f) {
    unsigned u = __builtin_bit_cast(unsigned, f);
    u += 0x7fff + ((u >> 16) & 1);
    return (unsigned short)(u >> 16);
}

__device__ inline void gl_lds16(const unsigned short* g, unsigned short* lds) {
    __builtin_amdgcn_global_load_lds(
        (const __attribute__((address_space(1))) unsigned int*)g,
        (__attribute__((address_space(3))) unsigned int*)lds, 16, 0, 0);
}

// ---------------------------------------------------------------------------
// f32 -> bf16 straight cast (8 elems/thread)
// ---------------------------------------------------------------------------
__global__ void cast_bf16(const float* __restrict__ in,
                          unsigned short* __restrict__ out, int n8) {
    int i = blockIdx.x * blockDim.x + threadIdx.x;
    if (i >= n8) return;
    float4 v0 = ((const float4*)in)[i * 2];
    float4 v1 = ((const float4*)in)[i * 2 + 1];
    short8 o;
    o[0] = f2bf(v0.x); o[1] = f2bf(v0.y); o[2] = f2bf(v0.z); o[3] = f2bf(v0.w);
    o[4] = f2bf(v1.x); o[5] = f2bf(v1.y); o[6] = f2bf(v1.z); o[7] = f2bf(v1.w);
    ((short8*)out)[i] = o;
}

// ---------------------------------------------------------------------------
// W [K][N] f32  ->  out [rowoff + N][K] bf16   (transpose + cast), 64x64 tiles
// ---------------------------------------------------------------------------
__global__ __launch_bounds__(256) void transpose_cast(
        const float* __restrict__ W, unsigned short* __restrict__ out,
        int K, int N, int rowoff) {
    __shared__ unsigned short ts[64][66];
    const int bx = blockIdx.x, by = blockIdx.y, tid = threadIdx.x;
    #pragma unroll
    for (int s = 0; s < 16; ++s) {
        int idx = tid + s * 256;
        int kl = idx >> 6, nl = idx & 63;
        ts[kl][nl] = f2bf(W[(size_t)(by * 64 + kl) * N + bx * 64 + nl]);
    }
    __syncthreads();
    #pragma unroll
    for (int s = 0; s < 16; ++s) {
        int idx = tid + s * 256;
        int nl = idx >> 6, kl = idx & 63;
        out[(size_t)(rowoff + bx * 64 + nl) * K + by * 64 + kl] = ts[kl][nl];
    }
}

// ---------------------------------------------------------------------------
// bf16 MFMA GEMM, 128x64 tile, BK=32, global_load_lds staging, 4 waves x 32row.
// MODE 0: C = f32 [M][1024]  (O projection)
// MODE 1: merged QKV (N=1536): col-group <16: Q RoPE*QSCALE -> Cq [B][16][T][64]
//         16..19: K RoPE -> Ck [B][4][T][64];  20..23: V -> Cvt [B][4][64][T]
// ---------------------------------------------------------------------------
template <int MODE>
__global__ __launch_bounds__(256) void gemm_mfma(
        const unsigned short* __restrict__ A,
        const unsigned short* __restrict__ Bt,
        void* __restrict__ Cq, unsigned short* __restrict__ Ck,
        unsigned short* __restrict__ Cvt,
        const float* __restrict__ rc, const float* __restrict__ rs,
        int M, int N, int K) {
    __shared__ __align__(16) unsigned short As[128 * 32];
    __shared__ __align__(16) unsigned short Bs[64 * 32];
    const int tid = threadIdx.x;
    const int w = tid >> 6, l = tid & 63, lk = l & 15, lg = l >> 4;
    const int bx = blockIdx.x, by = blockIdx.y;

    const unsigned short* Arow = A + (size_t)by * 128 * K;
    const unsigned short* Brow = Bt + (size_t)bx * 64 * K;

    f32x4 acc[2][4];
    #pragma unroll
    for (int m = 0; m < 2; ++m)
        #pragma unroll
        for (int n = 0; n < 4; ++n) acc[m][n] = (f32x4){0, 0, 0, 0};

    for (int k0 = 0; k0 < K; k0 += 32) {
        #pragma unroll
        for (int p = 0; p < 2; ++p) {
            int cb = p * 256 + w * 64;
            int c = cb + l;
            int row = c >> 2, ko = (c & 3) * 8;
            gl_lds16(Arow + (size_t)row * K + k0 + ko, As + cb * 8);
        }
        {
            int c = w * 64 + l;
            int row = c >> 2, ko = (c & 3) * 8;
            gl_lds16(Brow + (size_t)row * K + k0 + ko, Bs + c * 8);
        }
        __syncthreads();
        short8 aF[2], bF[4];
        #pragma unroll
        for (int m = 0; m < 2; ++m)
            aF[m] = *(const short8*)&As[(w * 32 + m * 16 + lk) * 32 + lg * 8];
        #pragma unroll
        for (int n = 0; n < 4; ++n)
            bF[n] = *(const short8*)&Bs[(n * 16 + lk) * 32 + lg * 8];
        #pragma unroll
        for (int m = 0; m < 2; ++m)
            #pragma unroll
            for (int n = 0; n < 4; ++n)
                acc[m][n] = __builtin_amdgcn_mfma_f32_16x16x32_bf16(
                    aF[m], bF[n], acc[m][n], 0, 0, 0);
        __syncthreads();
    }

    const int rowbase = by * 128 + w * 32;
    if constexpr (MODE == 0) {
        float* C = (float*)Cq;
        #pragma unroll
        for (int m = 0; m < 2; ++m)
            #pragma unroll
            for (int r = 0; r < 4; ++r) {
                size_t ro = (size_t)(rowbase + m * 16 + lg * 4 + r) * N + bx * 64 + lk;
                #pragma unroll
                for (int n = 0; n < 4; ++n) C[ro + n * 16] = acc[m][n][r];
            }
    }
    if constexpr (MODE == 1) {
        const int colgrp = bx;              // 64-col group over N=1536
        if (colgrp < 16) {                  // ---- Q: RoPE * QSCALE
            unsigned short* C = (unsigned short*)Cq;
            const int h = colgrp;
            #pragma unroll
            for (int m = 0; m < 2; ++m)
                #pragma unroll
                for (int r = 0; r < 4; ++r) {
                    int trow = rowbase + m * 16 + lg * 4 + r;
                    int b = trow >> 11, t = trow & (T_ - 1);
                    size_t ob = (((size_t)(b * 16 + h)) * T_ + t) * 64;
                    #pragma unroll
                    for (int n = 0; n < 2; ++n) {
                        int d = n * 16 + lk;
                        float cc = rc[t * 32 + d], ss = rs[t * 32 + d];
                        float x1 = acc[m][n][r], x2 = acc[m][n + 2][r];
                        C[ob + d]      = f2bf((x1 * cc - x2 * ss) * QSCALE);
                        C[ob + d + 32] = f2bf((x2 * cc + x1 * ss) * QSCALE);
                    }
                }
        } else if (colgrp < 20) {           // ---- K: RoPE
            const int kvh = colgrp - 16;
            #pragma unroll
            for (int m = 0; m < 2; ++m)
                #pragma unroll
                for (int r = 0; r < 4; ++r) {
                    int trow = rowbase + m * 16 + lg * 4 + r;
                    int b = trow >> 11, t = trow & (T_ - 1);
                    size_t ob = (((size_t)(b * 4 + kvh)) * T_ + t) * 64;
                    #pragma unroll
                    for (int n = 0; n < 2; ++n) {
                        int d = n * 16 + lk;
                        float cc = rc[t * 32 + d], ss = rs[t * 32 + d];
                        float x1 = acc[m][n][r], x2 = acc[m][n + 2][r];
                        Ck[ob + d]      = f2bf(x1 * cc - x2 * ss);
                        Ck[ob + d + 32] = f2bf(x2 * cc + x1 * ss);
                    }
                }
        } else {                            // ---- V -> [B][4][64][T]
            const int kvh = colgrp - 20;
            #pragma unroll
            for (int m = 0; m < 2; ++m) {
                int trow0 = rowbase + m * 16 + lg * 4;
                int b = trow0 >> 11, t0 = trow0 & (T_ - 1);
                #pragma unroll
                for (int n = 0; n < 4; ++n) {
                    int d = n * 16 + lk;
                    short4v pk;
                    #pragma unroll
                    for (int r = 0; r < 4; ++r) pk[r] = f2bf(acc[m][n][r]);
                    *(short4v*)(Cvt + (((size_t)(b * 4 + kvh)) * 64 + d) * T_ + t0) = pk;
                }
            }
        }
    }
}

// ---------------------------------------------------------------------------
// Flash attention v3: paired q-tiles, dual-tile-fused score/pv (K/V fragments
// loaded from LDS once, feed both tiles). Softmax in base-2 domain (exp2).
// ---------------------------------------------------------------------------
__global__ __launch_bounds__(256) void attn_mfma(
        const unsigned short* __restrict__ Q,   // [B][16][T][64] (pre-scaled, log2 domain)
        const unsigned short* __restrict__ K,   // [B][4][T][64]
        const unsigned short* __restrict__ Vt,  // [B][4][64][T]
        unsigned short* __restrict__ O) {       // [B*T][16][64] bf16
    __shared__ __align__(16) unsigned short Ks[2][64][68];
    __shared__ __align__(16) unsigned short Vs[2][64][68];
    __shared__ __align__(16) unsigned short Pl[2][4][16][68];

    const int bid = blockIdx.x;
    const int jp = bid & 15;
    const int h  = (bid >> 4) & 15;
    const int b  = bid >> 8;
    const int kv = h >> 2;
    const int qt0 = jp;          // short tile
    const int qt1 = 31 - jp;     // long tile
    const int tid = threadIdx.x;
    const int w = tid >> 6, l = tid & 63;
    const int lk = l & 15, lg = l >> 4;

    const unsigned short* Kb = K + ((size_t)(b * 4 + kv)) * T_ * 64;
    const unsigned short* Vb = Vt + ((size_t)(b * 4 + kv)) * 64 * T_;

    short8 af[2][2];
    {
        const unsigned short* q0 =
            Q + (((size_t)(b * 16 + h)) * T_ + qt0 * 64 + w * 16 + lk) * 64 + lg * 8;
        af[0][0] = *(const short8*)(q0);
        af[0][1] = *(const short8*)(q0 + 32);
        const unsigned short* q1 =
            Q + (((size_t)(b * 16 + h)) * T_ + qt1 * 64 + w * 16 + lk) * 64 + lg * 8;
        af[1][0] = *(const short8*)(q1);
        af[1][1] = *(const short8*)(q1 + 32);
    }

    f32x4 acc[2][4];
    f32x4 lacc[2];
    float mrow[2][4];
    #pragma unroll
    for (int ti = 0; ti < 2; ++ti) {
        lacc[ti] = (f32x4){0, 0, 0, 0};
        #pragma unroll
        for (int db = 0; db < 4; ++db) acc[ti][db] = (f32x4){0, 0, 0, 0};
        #pragma unroll
        for (int r = 0; r < 4; ++r) mrow[ti][r] = -1e38f;
    }

    short8 ones;
    #pragma unroll
    for (int i = 0; i < 8; ++i) ones[i] = (short)0x3F80;   // bf16 1.0

    const int srow = tid >> 2;            // 0..63
    const int soff = (tid & 3) * 16;      // 0,16,32,48

    short8 kr0, kr1, vr0, vr1;
    auto load_kv = [&](int kt) {
        const unsigned short* kg = Kb + ((size_t)(kt * 64 + srow)) * 64 + soff;
        kr0 = *(const short8*)(kg);
        kr1 = *(const short8*)(kg + 8);
        const unsigned short* vg = Vb + (size_t)srow * T_ + kt * 64 + soff;
        vr0 = *(const short8*)(vg);
        vr1 = *(const short8*)(vg + 8);
    };
    auto write_kv = [&](int buf) {
        *(short8*)(&Ks[buf][srow][soff])     = kr0;
        *(short8*)(&Ks[buf][srow][soff + 8]) = kr1;
        *(short8*)(&Vs[buf][srow][soff])     = vr0;
        *(short8*)(&Vs[buf][srow][soff + 8]) = vr1;
    };

    // online softmax for one tile; s4 in base-2 domain
    auto smax = [&](int ti, float (&s4)[4][4]) {
        #pragma unroll
        for (int r = 0; r < 4; ++r) {
            float rm = fmaxf(fmaxf(s4[0][r], s4[1][r]), fmaxf(s4[2][r], s4[3][r]));
            rm = fmaxf(rm, __shfl_xor(rm, 1));
            rm = fmaxf(rm, __shfl_xor(rm, 2));
            rm = fmaxf(rm, __shfl_xor(rm, 4));
            rm = fmaxf(rm, __shfl_xor(rm, 8));
            float nm = fmaxf(mrow[ti][r], rm);
            float corr = exp2f(mrow[ti][r] - nm);
            mrow[ti][r] = nm;
            #pragma unroll
            for (int nt = 0; nt < 4; ++nt) s4[nt][r] = exp2f(s4[nt][r] - nm);
            #pragma unroll
            for (int db = 0; db < 4; ++db) acc[ti][db][r] *= corr;
            lacc[ti][r] *= corr;
        }
        #pragma unroll
        for (int nt = 0; nt < 4; ++nt)
            #pragma unroll
            for (int r = 0; r < 4; ++r)
                Pl[ti][w][lg * 4 + r][nt * 16 + lk] = f2bf(s4[nt][r]);
    };

    auto mask_diag = [&](float (&s4)[4][4]) {
        int qloc = w * 16 + lg * 4;
        #pragma unroll
        for (int nt = 0; nt < 4; ++nt) {
            int kloc = nt * 16 + lk;
            #pragma unroll
            for (int r = 0; r < 4; ++r)
                if (kloc > qloc + r) s4[nt][r] = -1e30f;
        }
    };

    // dual-tile QK^T: K fragments read once, feed both tiles
    auto score_dual = [&](int kt, int cur) {
        float s0[4][4], s1[4][4];
        __builtin_amdgcn_s_setprio(1);
        #pragma unroll
        for (int nt = 0; nt < 4; ++nt) {
            short8 b0 = *(const short8*)(&Ks[cur][nt * 16 + lk][lg * 8]);
            short8 b1 = *(const short8*)(&Ks[cur][nt * 16 + lk][32 + lg * 8]);
            f32x4 c0 = {0, 0, 0, 0}, c1 = {0, 0, 0, 0};
            c0 = __builtin_amdgcn_mfma_f32_16x16x32_bf16(af[0][0], b0, c0, 0, 0, 0);
            c1 = __builtin_amdgcn_mfma_f32_16x16x32_bf16(af[1][0], b0, c1, 0, 0, 0);
            c0 = __builtin_amdgcn_mfma_f32_16x16x32_bf16(af[0][1], b1, c0, 0, 0, 0);
            c1 = __builtin_amdgcn_mfma_f32_16x16x32_bf16(af[1][1], b1, c1, 0, 0, 0);
            #pragma unroll
            for (int r = 0; r < 4; ++r) { s0[nt][r] = c0[r]; s1[nt][r] = c1[r]; }
        }
        __builtin_amdgcn_s_setprio(0);
        if (kt == qt0) mask_diag(s0);          // qt1 diag only in single path
        smax(0, s0);
        smax(1, s1);
    };
    auto score_one = [&](int kt, int cur) {
        float s1[4][4];
        __builtin_amdgcn_s_setprio(1);
        #pragma unroll
        for (int nt = 0; nt < 4; ++nt) {
            short8 b0 = *(const short8*)(&Ks[cur][nt * 16 + lk][lg * 8]);
            short8 b1 = *(const short8*)(&Ks[cur][nt * 16 + lk][32 + lg * 8]);
            f32x4 c1 = {0, 0, 0, 0};
            c1 = __builtin_amdgcn_mfma_f32_16x16x32_bf16(af[1][0], b0, c1, 0, 0, 0);
            c1 = __builtin_amdgcn_mfma_f32_16x16x32_bf16(af[1][1], b1, c1, 0, 0, 0);
            #pragma unroll
            for (int r = 0; r < 4; ++r) s1[nt][r] = c1[r];
        }
        __builtin_amdgcn_s_setprio(0);
        if (kt == qt1) mask_diag(s1);
        smax(1, s1);
    };
    // dual-tile PV: V fragments read once, feed both accs
    auto pv_dual = [&](int cur) {
        __builtin_amdgcn_s_setprio(1);
        #pragma unroll
        for (int kk = 0; kk < 2; ++kk) {
            short8 pa0 = *(const short8*)(&Pl[0][w][lk][kk * 32 + lg * 8]);
            short8 pa1 = *(const short8*)(&Pl[1][w][lk][kk * 32 + lg * 8]);
            lacc[0] = __builtin_amdgcn_mfma_f32_16x16x32_bf16(pa0, ones, lacc[0], 0, 0, 0);
            lacc[1] = __builtin_amdgcn_mfma_f32_16x16x32_bf16(pa1, ones, lacc[1], 0, 0, 0);
            #pragma unroll
            for (int db = 0; db < 4; ++db) {
                short8 vb = *(const short8*)(&Vs[cur][db * 16 + lk][kk * 32 + lg * 8]);
                acc[0][db] = __builtin_amdgcn_mfma_f32_16x16x32_bf16(pa0, vb, acc[0][db], 0, 0, 0);
                acc[1][db] = __builtin_amdgcn_mfma_f32_16x16x32_bf16(pa1, vb, acc[1][db], 0, 0, 0);
            }
        }
        __builtin_amdgcn_s_setprio(0);
    };
    auto pv_one = [&](int cur) {
        __builtin_amdgcn_s_setprio(1);
        #pragma unroll
        for (int kk = 0; kk < 2; ++kk) {
            short8 pa1 = *(const short8*)(&Pl[1][w][lk][kk * 32 + lg * 8]);
            lacc[1] = __builtin_amdgcn_mfma_f32_16x16x32_bf16(pa1, ones, lacc[1], 0, 0, 0);
            #pragma unroll
            for (int db = 0; db < 4; ++db) {
                short8 vb = *(const short8*)(&Vs[cur][db * 16 + lk][kk * 32 + lg * 8]);
                acc[1][db] = __builtin_amdgcn_mfma_f32_16x16x32_bf16(pa1, vb, acc[1][db], 0, 0, 0);
            }
        }
        __builtin_amdgcn_s_setprio(0);
    };

    load_kv(0);
    write_kv(0);
    for (int kt = 0; kt <= qt1; ++kt) {
        const int cur = kt & 1;
        __syncthreads();                        // staging of buf[cur] visible
        const bool pf = kt < qt1;
        if (pf) load_kv(kt + 1);                // issue early (T14)
        if (kt <= qt0) {
            score_dual(kt, cur);
            if (pf) write_kv(cur ^ 1);          // write late, covered by compute
            pv_dual(cur);
        } else {
            score_one(kt, cur);
            if (pf) write_kv(cur ^ 1);
            pv_one(cur);
        }
    }

    #pragma unroll
    for (int ti = 0; ti < 2; ++ti) {
        const int qt = ti ? qt1 : qt0;
        #pragma unroll
        for (int r = 0; r < 4; ++r) {
            float inv = 1.f / lacc[ti][r];
            int t = qt * 64 + w * 16 + lg * 4 + r;
            #pragma unroll
            for (int db = 0; db < 4; ++db)
                O[(((size_t)(b * T_ + t)) * 16 + h) * 64 + db * 16 + lk] =
                    f2bf(acc[ti][db][r] * inv);
        }
    }
}

// ---------------------------------------------------------------------------
extern "C" void kernel_launch(void* const* d_in, const int* in_sizes, int n_in,
                              void* d_out, int out_size, void* d_ws, size_t ws_size,
                              hipStream_t stream) {
    const float* x  = (const float*)d_in[0];
    const float* rc = (const float*)d_in[1];
    const float* rs = (const float*)d_in[2];
    const float* Wq = (const float*)d_in[4];
    const float* Wk = (const float*)d_in[5];
    const float* Wv = (const float*)d_in[6];
    const float* Wo = (const float*)d_in[7];
    float* out = (float*)d_out;

    unsigned short* ws = (unsigned short*)d_ws;
    unsigned short* xb  = ws;                        // 4M
    unsigned short* Wt  = ws + 4194304;              // 1536x1024 = 1.5M
    unsigned short* Wot = ws + 5767168;              // 1M
    unsigned short* Qbf = ws + 6815744;              // 4M
    unsigned short* Kbf = ws + 11010048;             // 1M
    unsigned short* Vtb = ws + 12058624;             // 1M
    unsigned short* Ob  = ws + 13107200;             // 4M

    dim3 blk(256);
    cast_bf16<<<2048, blk, 0, stream>>>(x, xb, 524288);
    transpose_cast<<<dim3(16, 16), blk, 0, stream>>>(Wq, Wt, 1024, 1024, 0);
    transpose_cast<<<dim3(4, 16),  blk, 0, stream>>>(Wk, Wt, 1024, 256, 1024);
    transpose_cast<<<dim3(4, 16),  blk, 0, stream>>>(Wv, Wt, 1024, 256, 1280);
    transpose_cast<<<dim3(16, 16), blk, 0, stream>>>(Wo, Wot, 1024, 1024, 0);

    gemm_mfma<1><<<dim3(24, 32), blk, 0, stream>>>(
        xb, Wt, (void*)Qbf, Kbf, Vtb, rc, rs, 4096, 1536, 1024);

    attn_mfma<<<dim3(2 * H_ * 16), blk, 0, stream>>>(Qbf, Kbf, Vtb, Ob);

    gemm_mfma<0><<<dim3(16, 32), blk, 0, stream>>>(
        Ob, Wot, (void*)out, nullptr, nullptr, nullptr, nullptr, 4096, 1024, 1024);
}

// Round 6
// 129.819 us; speedup vs baseline: 39.9280x; 1.1135x over previous
//
#include <hip/hip_runtime.h>

typedef __attribute__((ext_vector_type(8))) short short8;
typedef __attribute__((ext_vector_type(4))) short short4v;
typedef __attribute__((ext_vector_type(4))) float f32x4;

#define T_ 2048
#define H_ 16
#define KVH_ 4
#define QSCALE 0.18033688011112042f   // 0.125 * log2(e): softmax in base-2 domain
#define DEFER 8.0f                    // T13 defer-max threshold (log2 domain)

__device__ inline unsigned short f2bf(float f) {
    unsigned u = __builtin_bit_cast(unsigned, f);
    u += 0x7fff + ((u >> 16) & 1);
    return (unsigned short)(u >> 16);
}

__device__ inline void gl_lds16(const unsigned short* g, unsigned short* lds) {
    __builtin_amdgcn_global_load_lds(
        (const __attribute__((address_space(1))) unsigned int*)g,
        (__attribute__((address_space(3))) unsigned int*)lds, 16, 0, 0);
}

// ---------------------------------------------------------------------------
// f32 -> bf16 straight cast (8 elems/thread)
// ---------------------------------------------------------------------------
__global__ void cast_bf16(const float* __restrict__ in,
                          unsigned short* __restrict__ out, int n8) {
    int i = blockIdx.x * blockDim.x + threadIdx.x;
    if (i >= n8) return;
    float4 v0 = ((const float4*)in)[i * 2];
    float4 v1 = ((const float4*)in)[i * 2 + 1];
    short8 o;
    o[0] = f2bf(v0.x); o[1] = f2bf(v0.y); o[2] = f2bf(v0.z); o[3] = f2bf(v0.w);
    o[4] = f2bf(v1.x); o[5] = f2bf(v1.y); o[6] = f2bf(v1.z); o[7] = f2bf(v1.w);
    ((short8*)out)[i] = o;
}

// ---------------------------------------------------------------------------
// W [K][N] f32  ->  out [rowoff + N][K] bf16   (transpose + cast), 64x64 tiles
// ---------------------------------------------------------------------------
__global__ __launch_bounds__(256) void transpose_cast(
        const float* __restrict__ W, unsigned short* __restrict__ out,
        int K, int N, int rowoff) {
    __shared__ unsigned short ts[64][66];
    const int bx = blockIdx.x, by = blockIdx.y, tid = threadIdx.x;
    #pragma unroll
    for (int s = 0; s < 16; ++s) {
        int idx = tid + s * 256;
        int kl = idx >> 6, nl = idx & 63;
        ts[kl][nl] = f2bf(W[(size_t)(by * 64 + kl) * N + bx * 64 + nl]);
    }
    __syncthreads();
    #pragma unroll
    for (int s = 0; s < 16; ++s) {
        int idx = tid + s * 256;
        int nl = idx >> 6, kl = idx & 63;
        out[(size_t)(rowoff + bx * 64 + nl) * K + by * 64 + kl] = ts[kl][nl];
    }
}

// ---------------------------------------------------------------------------
// bf16 MFMA GEMM, 128x64 tile, BK=32, global_load_lds staging, 4 waves x 32row.
// MODE 0: C = f32 [M][1024]  (O projection)
// MODE 1: merged QKV (N=1536): col-group <16: Q RoPE*QSCALE -> Cq [B][16][T][64]
//         16..19: K RoPE -> Ck [B][4][T][64];  20..23: V -> Cvt [B][4][64][T]
// ---------------------------------------------------------------------------
template <int MODE>
__global__ __launch_bounds__(256) void gemm_mfma(
        const unsigned short* __restrict__ A,
        const unsigned short* __restrict__ Bt,
        void* __restrict__ Cq, unsigned short* __restrict__ Ck,
        unsigned short* __restrict__ Cvt,
        const float* __restrict__ rc, const float* __restrict__ rs,
        int M, int N, int K) {
    __shared__ __align__(16) unsigned short As[128 * 32];
    __shared__ __align__(16) unsigned short Bs[64 * 32];
    const int tid = threadIdx.x;
    const int w = tid >> 6, l = tid & 63, lk = l & 15, lg = l >> 4;
    const int bx = blockIdx.x, by = blockIdx.y;

    const unsigned short* Arow = A + (size_t)by * 128 * K;
    const unsigned short* Brow = Bt + (size_t)bx * 64 * K;

    f32x4 acc[2][4];
    #pragma unroll
    for (int m = 0; m < 2; ++m)
        #pragma unroll
        for (int n = 0; n < 4; ++n) acc[m][n] = (f32x4){0, 0, 0, 0};

    for (int k0 = 0; k0 < K; k0 += 32) {
        #pragma unroll
        for (int p = 0; p < 2; ++p) {
            int cb = p * 256 + w * 64;
            int c = cb + l;
            int row = c >> 2, ko = (c & 3) * 8;
            gl_lds16(Arow + (size_t)row * K + k0 + ko, As + cb * 8);
        }
        {
            int c = w * 64 + l;
            int row = c >> 2, ko = (c & 3) * 8;
            gl_lds16(Brow + (size_t)row * K + k0 + ko, Bs + c * 8);
        }
        __syncthreads();
        short8 aF[2], bF[4];
        #pragma unroll
        for (int m = 0; m < 2; ++m)
            aF[m] = *(const short8*)&As[(w * 32 + m * 16 + lk) * 32 + lg * 8];
        #pragma unroll
        for (int n = 0; n < 4; ++n)
            bF[n] = *(const short8*)&Bs[(n * 16 + lk) * 32 + lg * 8];
        #pragma unroll
        for (int m = 0; m < 2; ++m)
            #pragma unroll
            for (int n = 0; n < 4; ++n)
                acc[m][n] = __builtin_amdgcn_mfma_f32_16x16x32_bf16(
                    aF[m], bF[n], acc[m][n], 0, 0, 0);
        __syncthreads();
    }

    const int rowbase = by * 128 + w * 32;
    if constexpr (MODE == 0) {
        float* C = (float*)Cq;
        #pragma unroll
        for (int m = 0; m < 2; ++m)
            #pragma unroll
            for (int r = 0; r < 4; ++r) {
                size_t ro = (size_t)(rowbase + m * 16 + lg * 4 + r) * N + bx * 64 + lk;
                #pragma unroll
                for (int n = 0; n < 4; ++n) C[ro + n * 16] = acc[m][n][r];
            }
    }
    if constexpr (MODE == 1) {
        const int colgrp = bx;              // 64-col group over N=1536
        if (colgrp < 16) {                  // ---- Q: RoPE * QSCALE
            unsigned short* C = (unsigned short*)Cq;
            const int h = colgrp;
            #pragma unroll
            for (int m = 0; m < 2; ++m)
                #pragma unroll
                for (int r = 0; r < 4; ++r) {
                    int trow = rowbase + m * 16 + lg * 4 + r;
                    int b = trow >> 11, t = trow & (T_ - 1);
                    size_t ob = (((size_t)(b * 16 + h)) * T_ + t) * 64;
                    #pragma unroll
                    for (int n = 0; n < 2; ++n) {
                        int d = n * 16 + lk;
                        float cc = rc[t * 32 + d], ss = rs[t * 32 + d];
                        float x1 = acc[m][n][r], x2 = acc[m][n + 2][r];
                        C[ob + d]      = f2bf((x1 * cc - x2 * ss) * QSCALE);
                        C[ob + d + 32] = f2bf((x2 * cc + x1 * ss) * QSCALE);
                    }
                }
        } else if (colgrp < 20) {           // ---- K: RoPE
            const int kvh = colgrp - 16;
            #pragma unroll
            for (int m = 0; m < 2; ++m)
                #pragma unroll
                for (int r = 0; r < 4; ++r) {
                    int trow = rowbase + m * 16 + lg * 4 + r;
                    int b = trow >> 11, t = trow & (T_ - 1);
                    size_t ob = (((size_t)(b * 4 + kvh)) * T_ + t) * 64;
                    #pragma unroll
                    for (int n = 0; n < 2; ++n) {
                        int d = n * 16 + lk;
                        float cc = rc[t * 32 + d], ss = rs[t * 32 + d];
                        float x1 = acc[m][n][r], x2 = acc[m][n + 2][r];
                        Ck[ob + d]      = f2bf(x1 * cc - x2 * ss);
                        Ck[ob + d + 32] = f2bf(x2 * cc + x1 * ss);
                    }
                }
        } else {                            // ---- V -> [B][4][64][T]
            const int kvh = colgrp - 20;
            #pragma unroll
            for (int m = 0; m < 2; ++m) {
                int trow0 = rowbase + m * 16 + lg * 4;
                int b = trow0 >> 11, t0 = trow0 & (T_ - 1);
                #pragma unroll
                for (int n = 0; n < 4; ++n) {
                    int d = n * 16 + lk;
                    short4v pk;
                    #pragma unroll
                    for (int r = 0; r < 4; ++r) pk[r] = f2bf(acc[m][n][r]);
                    *(short4v*)(Cvt + (((size_t)(b * 4 + kvh)) * 64 + d) * T_ + t0) = pk;
                }
            }
        }
    }
}

// ---------------------------------------------------------------------------
// Flash attention v4: one 64-row q-tile per block, grid 1024 (4 blocks/CU),
// statically balanced qt mapping; XOR-swizzled LDS (40960 B); defer-max.
// ---------------------------------------------------------------------------
#define SW(row, col) ((col) ^ (((row) & 7) << 3))

__global__ __launch_bounds__(256) void attn_mfma(
        const unsigned short* __restrict__ Q,   // [B][16][T][64] (pre-scaled, log2 domain)
        const unsigned short* __restrict__ K,   // [B][4][T][64]
        const unsigned short* __restrict__ Vt,  // [B][4][64][T]
        unsigned short* __restrict__ O) {       // [B*T][16][64] bf16
    __shared__ __align__(16) unsigned short Ks[2][64][64];
    __shared__ __align__(16) unsigned short Vs[2][64][64];
    __shared__ __align__(16) unsigned short Pl[4][16][64];

    const int bid = blockIdx.x;
    const int bh = bid & 31;                 // (b,h)
    const int u  = bid >> 5;                 // 0..31
    // balanced mapping: CU-sets {k,15-k,16+k,31-k} sum to equal work
    const int g = u >> 3, k = u & 7;
    const int qt = (g == 0) ? k : (g == 1) ? 15 - k : (g == 2) ? 16 + k : 31 - k;
    const int h = bh & 15;
    const int b = bh >> 4;
    const int kv = h >> 2;
    const int tid = threadIdx.x;
    const int w = tid >> 6, l = tid & 63;
    const int lk = l & 15, lg = l >> 4;

    const unsigned short* Kb = K + ((size_t)(b * 4 + kv)) * T_ * 64;
    const unsigned short* Vb = Vt + ((size_t)(b * 4 + kv)) * 64 * T_;

    short8 af0, af1;
    {
        const unsigned short* q0 =
            Q + (((size_t)(b * 16 + h)) * T_ + qt * 64 + w * 16 + lk) * 64 + lg * 8;
        af0 = *(const short8*)(q0);
        af1 = *(const short8*)(q0 + 32);
    }

    f32x4 acc[4];
    f32x4 lacc = {0, 0, 0, 0};
    float mrow[4];
    #pragma unroll
    for (int db = 0; db < 4; ++db) acc[db] = (f32x4){0, 0, 0, 0};
    #pragma unroll
    for (int r = 0; r < 4; ++r) mrow[r] = -1e38f;

    short8 ones;
    #pragma unroll
    for (int i = 0; i < 8; ++i) ones[i] = (short)0x3F80;   // bf16 1.0

    const int srow = tid >> 2;            // 0..63
    const int soff = (tid & 3) * 16;      // 0,16,32,48

    short8 kr0, kr1, vr0, vr1;
    auto load_kv = [&](int kt) {
        const unsigned short* kg = Kb + ((size_t)(kt * 64 + srow)) * 64 + soff;
        kr0 = *(const short8*)(kg);
        kr1 = *(const short8*)(kg + 8);
        const unsigned short* vg = Vb + (size_t)srow * T_ + kt * 64 + soff;
        vr0 = *(const short8*)(vg);
        vr1 = *(const short8*)(vg + 8);
    };
    auto write_kv = [&](int buf) {
        *(short8*)(&Ks[buf][srow][SW(srow, soff)])     = kr0;
        *(short8*)(&Ks[buf][srow][SW(srow, soff + 8)]) = kr1;
        *(short8*)(&Vs[buf][srow][SW(srow, soff)])     = vr0;
        *(short8*)(&Vs[buf][srow][SW(srow, soff + 8)]) = vr1;
    };

    for (int kt = 0; kt <= qt; ++kt) {
        const int cur = kt & 1;
        if (kt == 0) { load_kv(0); write_kv(0); }
        __syncthreads();                        // staging of buf[cur] visible
        const bool pf = kt < qt;
        if (pf) load_kv(kt + 1);                // issue early (T14)

        // ---- S = Q K^T
        float s4[4][4];
        __builtin_amdgcn_s_setprio(1);
        #pragma unroll
        for (int nt = 0; nt < 4; ++nt) {
            const int row = nt * 16 + lk;
            short8 b0 = *(const short8*)(&Ks[cur][row][SW(row, lg * 8)]);
            short8 b1 = *(const short8*)(&Ks[cur][row][SW(row, 32 + lg * 8)]);
            f32x4 c = {0, 0, 0, 0};
            c = __builtin_amdgcn_mfma_f32_16x16x32_bf16(af0, b0, c, 0, 0, 0);
            c = __builtin_amdgcn_mfma_f32_16x16x32_bf16(af1, b1, c, 0, 0, 0);
            #pragma unroll
            for (int r = 0; r < 4; ++r) s4[nt][r] = c[r];
        }
        __builtin_amdgcn_s_setprio(0);

        if (kt == qt) {                         // diagonal mask
            int qloc = w * 16 + lg * 4;
            #pragma unroll
            for (int nt = 0; nt < 4; ++nt) {
                int kloc = nt * 16 + lk;
                #pragma unroll
                for (int r = 0; r < 4; ++r)
                    if (kloc > qloc + r) s4[nt][r] = -1e30f;
            }
        }

        // ---- online softmax with defer-max (T13)
        float rm[4];
        #pragma unroll
        for (int r = 0; r < 4; ++r) {
            float v = fmaxf(fmaxf(s4[0][r], s4[1][r]), fmaxf(s4[2][r], s4[3][r]));
            v = fmaxf(v, __shfl_xor(v, 1));
            v = fmaxf(v, __shfl_xor(v, 2));
            v = fmaxf(v, __shfl_xor(v, 4));
            v = fmaxf(v, __shfl_xor(v, 8));
            rm[r] = v;
        }
        bool need = (rm[0] > mrow[0] + DEFER) || (rm[1] > mrow[1] + DEFER) ||
                    (rm[2] > mrow[2] + DEFER) || (rm[3] > mrow[3] + DEFER);
        if (__any(need)) {
            #pragma unroll
            for (int r = 0; r < 4; ++r) {
                float nm = fmaxf(mrow[r], rm[r]);
                float corr = exp2f(mrow[r] - nm);
                mrow[r] = nm;
                #pragma unroll
                for (int db = 0; db < 4; ++db) acc[db][r] *= corr;
                lacc[r] *= corr;
            }
        }
        #pragma unroll
        for (int r = 0; r < 4; ++r)
            #pragma unroll
            for (int nt = 0; nt < 4; ++nt) s4[nt][r] = exp2f(s4[nt][r] - mrow[r]);

        #pragma unroll
        for (int nt = 0; nt < 4; ++nt)
            #pragma unroll
            for (int r = 0; r < 4; ++r) {
                int row = lg * 4 + r;
                Pl[w][row][SW(row, nt * 16 + lk)] = f2bf(s4[nt][r]);
            }

        if (pf) write_kv(cur ^ 1);              // write late, covered by compute

        // ---- O += P V ; lsum += P 1
        __builtin_amdgcn_s_setprio(1);
        #pragma unroll
        for (int kk = 0; kk < 2; ++kk) {
            short8 pa = *(const short8*)(&Pl[w][lk][SW(lk, kk * 32 + lg * 8)]);
            lacc = __builtin_amdgcn_mfma_f32_16x16x32_bf16(pa, ones, lacc, 0, 0, 0);
            #pragma unroll
            for (int db = 0; db < 4; ++db) {
                const int row = db * 16 + lk;
                short8 vb = *(const short8*)(&Vs[cur][row][SW(row, kk * 32 + lg * 8)]);
                acc[db] = __builtin_amdgcn_mfma_f32_16x16x32_bf16(pa, vb, acc[db], 0, 0, 0);
            }
        }
        __builtin_amdgcn_s_setprio(0);
    }

    #pragma unroll
    for (int r = 0; r < 4; ++r) {
        float inv = 1.f / lacc[r];
        int t = qt * 64 + w * 16 + lg * 4 + r;
        #pragma unroll
        for (int db = 0; db < 4; ++db)
            O[(((size_t)(b * T_ + t)) * 16 + h) * 64 + db * 16 + lk] =
                f2bf(acc[db][r] * inv);
    }
}

// ---------------------------------------------------------------------------
extern "C" void kernel_launch(void* const* d_in, const int* in_sizes, int n_in,
                              void* d_out, int out_size, void* d_ws, size_t ws_size,
                              hipStream_t stream) {
    const float* x  = (const float*)d_in[0];
    const float* rc = (const float*)d_in[1];
    const float* rs = (const float*)d_in[2];
    const float* Wq = (const float*)d_in[4];
    const float* Wk = (const float*)d_in[5];
    const float* Wv = (const float*)d_in[6];
    const float* Wo = (const float*)d_in[7];
    float* out = (float*)d_out;

    unsigned short* ws = (unsigned short*)d_ws;
    unsigned short* xb  = ws;                        // 4M
    unsigned short* Wt  = ws + 4194304;              // 1536x1024 = 1.5M
    unsigned short* Wot = ws + 5767168;              // 1M
    unsigned short* Qbf = ws + 6815744;              // 4M
    unsigned short* Kbf = ws + 11010048;             // 1M
    unsigned short* Vtb = ws + 12058624;             // 1M
    unsigned short* Ob  = ws + 13107200;             // 4M

    dim3 blk(256);
    cast_bf16<<<2048, blk, 0, stream>>>(x, xb, 524288);
    transpose_cast<<<dim3(16, 16), blk, 0, stream>>>(Wq, Wt, 1024, 1024, 0);
    transpose_cast<<<dim3(4, 16),  blk, 0, stream>>>(Wk, Wt, 1024, 256, 1024);
    transpose_cast<<<dim3(4, 16),  blk, 0, stream>>>(Wv, Wt, 1024, 256, 1280);
    transpose_cast<<<dim3(16, 16), blk, 0, stream>>>(Wo, Wot, 1024, 1024, 0);

    gemm_mfma<1><<<dim3(24, 32), blk, 0, stream>>>(
        xb, Wt, (void*)Qbf, Kbf, Vtb, rc, rs, 4096, 1536, 1024);

    attn_mfma<<<dim3(1024), blk, 0, stream>>>(Qbf, Kbf, Vtb, Ob);

    gemm_mfma<0><<<dim3(16, 32), blk, 0, stream>>>(
        Ob, Wot, (void*)out, nullptr, nullptr, nullptr, nullptr, 4096, 1024, 1024);
}